// Round 17
// baseline (106.057 us; speedup 1.0000x reference)
//
#include <hip/hip_runtime.h>

// FixedSparseMultiHead: B=2, S=2048, D=1024, H=16, Hd=64, local band ±102.
// Round 17: r16 (105.9us verified) + qkvf XCD partition flipped to n-major.
//   Old: XCD owns 4 m-tiles x all 16 n-tiles -> 6MB W re-read 4x, thrashes
//        the 4MB per-XCD L2 (the stuck 4275 cyc/step = W re-fetch latency).
//   New: XCD owns 2 n-tiles x all 32 m-tiles -> 0.75MB W L2-resident (32x
//        reuse), x streamed 2x. W staging loads become L2 hits.
//   Per-block computation identical -> absmax bit-identical.
// Pipeline: split5 -> gemm_qkvf -> attn_mfma (swizzled shared-K) -> gemm_out.
// Fallback fp32 path if ws_size < 80MB.

#define SEQ    2048
#define DMODEL 1024
#define NHEAD  16
#define HDIM   64
#define HALFW  102
#define BWMAX  240
#define VTS    2176    // padded V^T row stride (zeros beyond SEQ)

typedef unsigned short u16;
typedef __attribute__((ext_vector_type(8))) short bf16x8;
typedef __attribute__((ext_vector_type(8))) _Float16 f16x8;
typedef __attribute__((ext_vector_type(4))) float f32x4;

#define VMW12() asm volatile("s_waitcnt vmcnt(12)" ::: "memory")
#define VMW10() asm volatile("s_waitcnt vmcnt(10)" ::: "memory")
#define VMW8()  asm volatile("s_waitcnt vmcnt(8)"  ::: "memory")
#define VMW5()  asm volatile("s_waitcnt vmcnt(5)"  ::: "memory")
#define VMW4()  asm volatile("s_waitcnt vmcnt(4)"  ::: "memory")
#define VMW0()  asm volatile("s_waitcnt vmcnt(0)"  ::: "memory")
#define BARR()  __builtin_amdgcn_s_barrier()
#define CFENCE() asm volatile("" ::: "memory")

__device__ __forceinline__ u16 f2bf(float f) {
    unsigned u = __builtin_bit_cast(unsigned, f);
    unsigned r = (u + 0x7fffu + ((u >> 16) & 1u)) >> 16;   // RNE
    return (u16)r;
}
__device__ __forceinline__ float bf2f(u16 u) {
    return __builtin_bit_cast(float, ((unsigned)u) << 16);
}
__device__ __forceinline__ u16 f2h(float f) {
    return __builtin_bit_cast(u16, (_Float16)f);           // RNE
}

__device__ __forceinline__ void gload16(const void* g, void* l) {
    __builtin_amdgcn_global_load_lds(
        (const __attribute__((address_space(1))) void*)g,
        (__attribute__((address_space(3))) void*)l, 16, 0, 0);
}

// ---------------------------------------------------------------------------
// split: fp32 -> fp16. 1-D exact grid 8192: bx<4096 -> x; else weights.
// ---------------------------------------------------------------------------
__global__ __launch_bounds__(256) void split5(
    const float* __restrict__ x,  const float* __restrict__ wq,
    const float* __restrict__ wk, const float* __restrict__ wv,
    const float* __restrict__ wo,
    u16* __restrict__ xh, u16* __restrict__ wbase)
{
    const int bx = blockIdx.x;
    const float* src; u16* dst; int blk;
    if (bx < 4096) {
        src = x; dst = xh; blk = bx;
    } else {
        const int w = (bx - 4096) >> 10;         // 0..3
        blk = (bx - 4096) & 1023;
        switch (w) {
          case 0:  src = wq; dst = wbase;           break;
          case 1:  src = wk; dst = wbase + 1048576; break;
          case 2:  src = wv; dst = wbase + 2097152; break;
          default: src = wo; dst = wbase + 3145728; break;
        }
    }
    const int i = (blk * 256 + threadIdx.x) * 4;
    const float4 v = *(const float4*)(src + i);
    ushort4 h;
    h.x = f2h(v.x); h.y = f2h(v.y); h.z = f2h(v.z); h.w = f2h(v.w);
    *(ushort4*)(dst + i) = h;
}

// ---------------------------------------------------------------------------
// FUSED Q/K/V^T projection. Grid 512, 256 thr = 4 waves (2m x 2n over
// 128x64). x-tile staged once for 3 products. BK=32, 32 steps.
// LDS: sA[4][4096] + sB[4][3][2048] = 80 KB -> 2 blk/CU.
// Dist-2 counted vmcnt, one barrier/step (safety proof verified r8/r13).
// XCD partition n-major: XCD owns 2 n-tiles x all 32 m-tiles (W L2-resident).
// ---------------------------------------------------------------------------
__global__ __launch_bounds__(256) void gemm_qkvf(
    const u16* __restrict__ xh, const u16* __restrict__ wbase,
    const float* __restrict__ bq, const float* __restrict__ bk,
    const float* __restrict__ bvv,
    u16* __restrict__ Qo, u16* __restrict__ Ko, u16* __restrict__ VTo)
{
    __shared__ u16 sA[4][4096];      // 32 KB
    __shared__ u16 sB[4][3][2048];   // 48 KB

    const int tid = threadIdx.x, ln = tid & 63, wv = tid >> 6;
    const int wm = wv >> 1, wn = wv & 1;
    const int srow = ln & 15, scol = (ln >> 4) * 8;

    const int bx = blockIdx.x;                  // 512 = 8 XCD x 2 nt x 32 mt
    const int nt = (bx & 7) * 2 + ((bx >> 3) & 1);
    const int mt = bx >> 4;                     // 0..31
    const int m0 = mt * 128, n0 = nt * 64;

    f32x4 acc[3][4][2];
#pragma unroll
    for (int y = 0; y < 3; ++y)
#pragma unroll
        for (int fm = 0; fm < 4; ++fm)
#pragma unroll
            for (int fn = 0; fn < 2; ++fn) acc[y][fm][fn] = (f32x4){0.f, 0.f, 0.f, 0.f};

    auto stage = [&](int s) {
        const int buf = s & 3, k0 = s << 5;
#pragma unroll
        for (int i = 0; i < 2; ++i) {           // A: 8 chunks / 4 waves
            const int c = wv * 2 + i;
            gload16(xh + (size_t)(m0 + c * 16 + srow) * 1024 + k0 + scol,
                    sA[buf] + c * 512);
        }
#pragma unroll
        for (int i = 0; i < 3; ++i) {           // B: 12 chunks (3y x 4g) / 4 waves
            const int c = wv * 3 + i;           // 0..11, bijective
            const int yy = c >> 2, g = c & 3;
            gload16(wbase + (size_t)yy * 1048576
                          + (size_t)(n0 + g * 16 + srow) * 1024 + k0 + scol,
                    sB[buf][yy] + g * 512);
        }
    };

    stage(0); stage(1);

    for (int t = 0; t < 32; ++t) {
        if (t + 2 < 32) stage(t + 2);
        if (t < 30)       VMW10();   // stages t+1,t+2 in flight (5 loads each)
        else if (t == 30) VMW5();
        else              VMW0();
        BARR();
        CFENCE();

        const int buf = t & 3;
        f16x8 a[4];
#pragma unroll
        for (int f = 0; f < 4; ++f)
            a[f] = *(const f16x8*)(sA[buf] + (wm * 4 + f) * 512 + ln * 8);
#pragma unroll
        for (int y = 0; y < 3; ++y) {
            f16x8 b[2];
#pragma unroll
            for (int f = 0; f < 2; ++f)
                b[f] = *(const f16x8*)(sB[buf][y] + (wn * 2 + f) * 512 + ln * 8);
#pragma unroll
            for (int fm = 0; fm < 4; ++fm)
#pragma unroll
                for (int fn = 0; fn < 2; ++fn)
                    acc[y][fm][fn] = __builtin_amdgcn_mfma_f32_16x16x32_f16(
                        a[fm], b[fn], acc[y][fm][fn], 0, 0, 0);
        }
    }

    const int rl = ln & 15, kh = ln >> 4;

    // ---- Q, K epilogue: bf16 [B,H,S,64] ----
#pragma unroll
    for (int y = 0; y < 2; ++y) {
        const float* bias = y ? bk : bq;
        u16* Y = y ? Ko : Qo;
#pragma unroll
        for (int fn = 0; fn < 2; ++fn) {
            const int n = n0 + wn * 32 + fn * 16 + rl;
            const float bb = bias[n];
            const int h = n >> 6, hd = n & 63;
#pragma unroll
            for (int fm = 0; fm < 4; ++fm)
#pragma unroll
                for (int r = 0; r < 4; ++r) {
                    const int m = m0 + wm * 64 + fm * 16 + kh * 4 + r;
                    const int b = m >> 11, s = m & (SEQ - 1);
                    Y[((size_t)(b * NHEAD + h) * SEQ + s) * HDIM + hd] =
                        f2bf(acc[y][fm][fn][r] + bb);
                }
        }
    }
    // ---- V^T epilogue: bf16 [B,H,64,VTS]; C[m=s][n=d] -> VT[d-row][s] ----
#pragma unroll
    for (int fn = 0; fn < 2; ++fn) {
        const int n = n0 + wn * 32 + fn * 16 + rl;   // d index
        const float bb = bvv[n];
        const int h = n >> 6, hd = n & 63;
#pragma unroll
        for (int fm = 0; fm < 4; ++fm)
#pragma unroll
            for (int r = 0; r < 4; ++r) {
                const int m = m0 + wm * 64 + fm * 16 + kh * 4 + r;   // seq index
                const int b = m >> 11, s = m & (SEQ - 1);
                VTo[((size_t)(b * NHEAD + h) * HDIM + hd) * VTS + s] =
                    f2bf(acc[2][fm][fn][r] + bb);
            }
    }
}

// ---------------------------------------------------------------------------
// Final projection (r13-verified): out = AO@Wo^T + bo, fp32 out.
// 5-buffer counted-vmcnt pipeline, BK=32, 128x128 tile, grid 256.
// ---------------------------------------------------------------------------
__device__ __forceinline__ void gemm_core_out(
    const u16* __restrict__ A, const u16* __restrict__ B,
    int m0, int n0, u16 (*sA)[4096], u16 (*sB)[4096], f32x4 acc[4][4])
{
    const int tid = threadIdx.x, ln = tid & 63, wave = tid >> 6;
    const int wm = wave >> 1, wn = wave & 1;
    const int srow = ln & 15, scol = (ln >> 4) * 8;

#pragma unroll
    for (int fm = 0; fm < 4; ++fm)
#pragma unroll
        for (int fn = 0; fn < 4; ++fn) acc[fm][fn] = (f32x4){0.f, 0.f, 0.f, 0.f};

    auto stage = [&](int s) {
        if (s >= 32) return;
        const int buf = s % 5;
        const int k0 = s << 5;
#pragma unroll
        for (int c = wave; c < 8; c += 4) {
            gload16(A + (size_t)(m0 + c * 16 + srow) * 1024 + k0 + scol, sA[buf] + c * 512);
            gload16(B + (size_t)(n0 + c * 16 + srow) * 1024 + k0 + scol, sB[buf] + c * 512);
        }
    };

    stage(0); stage(1); stage(2);

    int buf = 0;
    for (int t = 0; t < 32; ++t) {
        stage(t + 3);
        if (t < 29)       VMW12();
        else if (t == 29) VMW8();
        else if (t == 30) VMW4();
        else              VMW0();
        BARR();
        CFENCE();

        f16x8 a[4], b[4];
#pragma unroll
        for (int f = 0; f < 4; ++f) {
            a[f] = *(const f16x8*)(sA[buf] + (wm * 4 + f) * 512 + ln * 8);
            b[f] = *(const f16x8*)(sB[buf] + (wn * 4 + f) * 512 + ln * 8);
        }
#pragma unroll
        for (int fm = 0; fm < 4; ++fm)
#pragma unroll
            for (int fn = 0; fn < 4; ++fn)
                acc[fm][fn] = __builtin_amdgcn_mfma_f32_16x16x32_f16(
                    a[fm], b[fn], acc[fm][fn], 0, 0, 0);
        buf = (buf == 4) ? 0 : buf + 1;
    }
}

__global__ __launch_bounds__(256) void gemm_out(
    const u16* __restrict__ A, const u16* __restrict__ B,
    const float* __restrict__ bias, float* __restrict__ Y)
{
    __shared__ u16 sA[5][4096], sB[5][4096];   // 80 KB
    const int bx = blockIdx.x;
    const int mt = (bx & 7) * 4 + (bx >> 6);
    const int nt = (bx >> 3) & 7;
    const int m0 = mt * 128, n0 = nt * 128;

    f32x4 acc[4][4];
    gemm_core_out(A, B, m0, n0, sA, sB, acc);

    const int tid = threadIdx.x, ln = tid & 63, wave = tid >> 6;
    const int wm = wave >> 1, wn = wave & 1;
    const int rl = ln & 15, kh = ln >> 4;
#pragma unroll
    for (int fn = 0; fn < 4; ++fn) {
        const int n = n0 + wn * 64 + fn * 16 + rl;
        const float bb = bias[n];
#pragma unroll
        for (int fm = 0; fm < 4; ++fm)
#pragma unroll
            for (int r = 0; r < 4; ++r) {
                const int m = m0 + wm * 64 + fm * 16 + kh * 4 + r;
                Y[(size_t)m * DMODEL + n] = acc[fm][fn][r] + bb;
            }
    }
}

// ---------------------------------------------------------------------------
// MFMA banded attention v2 (r16-verified): block-shared swizzled K in LDS,
// P reuses the K buffer after a __syncthreads. 34 KB LDS -> 4 blocks/CU.
// ---------------------------------------------------------------------------
__global__ __launch_bounds__(256) void attn_mfma(
    const u16* __restrict__ Q, const u16* __restrict__ K,
    const u16* __restrict__ VT, u16* __restrict__ aoh)
{
    __shared__ u16 KP[17408];   // 34 KB: K (272 rows x 64 elem), then P

    const int tid = threadIdx.x, ln = tid & 63, wv = tid >> 6;
    const int bx0 = blockIdx.x;
    const int asg = (bx0 & 7) * 128 + (bx0 >> 3);   // 1024 = 8 XCD * 128
    const int bh  = asg >> 5;
    const int qt  = asg & 31;
    const int b   = bh >> 4, h = bh & 15;
    const int q0  = qt * 64 + wv * 16;
    const int jmin = (q0 >= 104) ? (q0 - 104) : 0;         // wave window base
    const int j0   = (qt * 64 >= 104) ? (qt * 64 - 104) : 0; // block window base
    const int woff = jmin - j0;

    const u16* Qbh  = Q  + (size_t)bh * SEQ * HDIM;
    const u16* Kbh  = K  + (size_t)bh * SEQ * HDIM;
    const u16* VTbh = VT + (size_t)bh * HDIM * VTS;

    const int lr = ln & 15, lk = ln >> 4;

    // ---- phase 0: stage K window, swizzled ----
    {
        const int sr = ln >> 3;                 // row within 8-row chunk
        const int scol = ((ln & 7) ^ sr) * 8;   // pre-swizzled source column
        for (int c = wv; c < 34; c += 4) {
            const int j = j0 + c * 8 + sr;
            const int jc = (j < SEQ) ? j : (SEQ - 1);
            gload16(Kbh + (size_t)jc * HDIM + scol, KP + c * 512);
        }
    }

    const bf16x8 qf0 = *(const bf16x8*)(Qbh + (size_t)(q0 + lr) * HDIM + lk * 8);
    const bf16x8 qf1 = *(const bf16x8*)(Qbh + (size_t)(q0 + lr) * HDIM + 32 + lk * 8);

    __syncthreads();   // K staged (drains vmcnt) before any wave reads it

    // ---- phase 1: QK^T from LDS ----
    f32x4 sc[14];
#pragma unroll
    for (int t = 0; t < 14; ++t) {
        const int row = woff + t * 16 + lr;     // <= 271
        const int s0 = lk ^ (row & 7);
        const int s1 = (4 + lk) ^ (row & 7);
        const bf16x8 k0 = *(const bf16x8*)(KP + row * 64 + s0 * 8);
        const bf16x8 k1 = *(const bf16x8*)(KP + row * 64 + s1 * 8);
        f32x4 a = (f32x4){0.f, 0.f, 0.f, 0.f};
        a = __builtin_amdgcn_mfma_f32_16x16x32_bf16(qf0, k0, a, 0, 0, 0);
        a = __builtin_amdgcn_mfma_f32_16x16x32_bf16(qf1, k1, a, 0, 0, 0);
        sc[t] = a;
    }

    __syncthreads();   // all waves done reading K; P may overwrite buffer

    // ---- phase 1.5: masked softmax; P -> KP as [4][16][232] ----
    u16* P = KP + wv * 3712;
    float lrow[4];
#pragma unroll
    for (int r = 0; r < 4; ++r) {
        const int i = q0 + lk * 4 + r;
        float mx = -3.0e38f;
#pragma unroll
        for (int t = 0; t < 14; ++t) {
            const int j = jmin + t * 16 + lr;
            float v = sc[t][r] * 0.125f;
            const bool ok = (j >= i - HALFW) && (j <= i + HALFW) && (j < SEQ);
            v = ok ? v : -3.0e38f;
            sc[t][r] = v;
            mx = fmaxf(mx, v);
        }
#pragma unroll
        for (int off = 8; off > 0; off >>= 1) mx = fmaxf(mx, __shfl_xor(mx, off));
        float sum = 0.f;
#pragma unroll
        for (int t = 0; t < 14; ++t) {
            const float p = __expf(sc[t][r] - mx);   // masked -> exactly 0
            sum += p;
            P[(lk * 4 + r) * 232 + t * 16 + lr] = f2bf(p);
        }
#pragma unroll
        for (int off = 8; off > 0; off >>= 1) sum += __shfl_xor(sum, off);
        lrow[r] = sum;
    }
    // same-wave LDS write->read below; compiler inserts lgkmcnt waits

    // ---- phase 2: PV, 7 k-chunks x 4 d-tiles, aligned V^T loads ----
    f32x4 ao[4];
#pragma unroll
    for (int nt = 0; nt < 4; ++nt) ao[nt] = (f32x4){0.f, 0.f, 0.f, 0.f};
#pragma unroll
    for (int kc = 0; kc < 7; ++kc) {
        const bf16x8 pf = *(const bf16x8*)(P + lr * 232 + kc * 32 + lk * 8);
        const int jb = jmin + kc * 32 + lk * 8;   // 16B aligned, < VTS
#pragma unroll
        for (int nt = 0; nt < 4; ++nt) {
            const bf16x8 vf = *(const bf16x8*)(VTbh + (size_t)(nt * 16 + lr) * VTS + jb);
            ao[nt] = __builtin_amdgcn_mfma_f32_16x16x32_bf16(pf, vf, ao[nt], 0, 0, 0);
        }
    }

    // ---- epilogue: AO -> fp16 [4096][1024] ----
#pragma unroll
    for (int nt = 0; nt < 4; ++nt)
#pragma unroll
        for (int r = 0; r < 4; ++r) {
            const int i = q0 + lk * 4 + r;
            const float o = ao[nt][r] / lrow[r];
            aoh[((size_t)b * SEQ + i) * DMODEL + h * HDIM + nt * 16 + lr] = f2h(o);
        }
}

// ---------------------------------------------------------------------------
// Round-1 fp32 path (fallback only).
// ---------------------------------------------------------------------------
template<int QKV>
__global__ __launch_bounds__(256) void gemm_xwt(
    const float* __restrict__ X, const float* __restrict__ W,
    const float* __restrict__ bias, float* __restrict__ Y)
{
    __shared__ float As[16][132];
    __shared__ float Bs[16][68];
    const int tid = threadIdx.x;
    const int bx  = blockIdx.x;
    const int n0  = (bx & 15) * 64;
    const int m0  = (bx >> 4) * 128;
    const int ty  = tid >> 4, tx = tid & 15;
    float acc[8][4];
#pragma unroll
    for (int r = 0; r < 8; ++r)
#pragma unroll
        for (int c = 0; c < 4; ++c) acc[r][c] = 0.f;
    const int lrow = tid >> 2, lkq = (tid & 3) * 4;
    for (int k0 = 0; k0 < DMODEL; k0 += 16) {
        float4 a0 = *(const float4*)(X + (size_t)(m0 + lrow)      * DMODEL + k0 + lkq);
        float4 a1 = *(const float4*)(X + (size_t)(m0 + lrow + 64) * DMODEL + k0 + lkq);
        float4 b0 = *(const float4*)(W + (size_t)(n0 + lrow)      * DMODEL + k0 + lkq);
        __syncthreads();
        As[lkq + 0][lrow] = a0.x; As[lkq + 1][lrow] = a0.y;
        As[lkq + 2][lrow] = a0.z; As[lkq + 3][lrow] = a0.w;
        As[lkq + 0][lrow + 64] = a1.x; As[lkq + 1][lrow + 64] = a1.y;
        As[lkq + 2][lrow + 64] = a1.z; As[lkq + 3][lrow + 64] = a1.w;
        Bs[lkq + 0][lrow] = b0.x; Bs[lkq + 1][lrow] = b0.y;
        Bs[lkq + 2][lrow] = b0.z; Bs[lkq + 3][lrow] = b0.w;
        __syncthreads();
#pragma unroll
        for (int k = 0; k < 16; ++k) {
            float4 av0 = *(const float4*)&As[k][ty * 8];
            float4 av1 = *(const float4*)&As[k][ty * 8 + 4];
            float4 bv  = *(const float4*)&Bs[k][tx * 4];
            float a[8] = {av0.x, av0.y, av0.z, av0.w, av1.x, av1.y, av1.z, av1.w};
            float bb[4] = {bv.x, bv.y, bv.z, bv.w};
#pragma unroll
            for (int r = 0; r < 8; ++r)
#pragma unroll
                for (int c = 0; c < 4; ++c) acc[r][c] += a[r] * bb[c];
        }
    }
    const float4 bb = *(const float4*)(bias + n0 + tx * 4);
    if (QKV) {
        const int b = m0 >> 11, h = n0 >> 6;
#pragma unroll
        for (int r = 0; r < 8; ++r) {
            const int m = m0 + ty * 8 + r, ss = m & (SEQ - 1);
            float4 o = {acc[r][0] + bb.x, acc[r][1] + bb.y, acc[r][2] + bb.z, acc[r][3] + bb.w};
            *(float4*)(Y + ((size_t)(b * NHEAD + h) * SEQ + ss) * HDIM + tx * 4) = o;
        }
    } else {
#pragma unroll
        for (int r = 0; r < 8; ++r) {
            const int m = m0 + ty * 8 + r;
            float4 o = {acc[r][0] + bb.x, acc[r][1] + bb.y, acc[r][2] + bb.z, acc[r][3] + bb.w};
            *(float4*)(Y + (size_t)m * DMODEL + n0 + tx * 4) = o;
        }
    }
}

__global__ __launch_bounds__(256) void attn_local_f32(
    const float* __restrict__ Q, const float* __restrict__ K,
    const float* __restrict__ V, float* __restrict__ O)
{
    __shared__ float ssc[32][BWMAX];
    const int tid = threadIdx.x;
    const int bx0 = blockIdx.x;
    const int bx  = (bx0 & 7) * 256 + (bx0 >> 3);
    const int qt  = bx & 63;
    const int h   = (bx >> 6) & 15;
    const int b   = bx >> 10;
    const int i0  = qt * 32;
    const int jmin = max(0, i0 - HALFW);
    const int jmax = min(SEQ - 1, i0 + 31 + HALFW);
    const int BWt  = jmax - jmin + 1;
    const float* Qbh = Q + (size_t)(b * NHEAD + h) * SEQ * HDIM;
    const float* Kbh = K + (size_t)(b * NHEAD + h) * SEQ * HDIM;
    const float* Vbh = V + (size_t)(b * NHEAD + h) * SEQ * HDIM;
    const int jj = tid;
    if (jj < BWt) {
        float acc[32];
#pragma unroll
        for (int i = 0; i < 32; ++i) acc[i] = 0.f;
        const float* kp = Kbh + (size_t)(jmin + jj) * HDIM;
        for (int d0 = 0; d0 < HDIM; d0 += 4) {
            const float4 kv = *(const float4*)(kp + d0);
#pragma unroll
            for (int i = 0; i < 32; ++i) {
                const float4 qv = *(const float4*)(Qbh + (size_t)(i0 + i) * HDIM + d0);
                acc[i] += qv.x * kv.x + qv.y * kv.y + qv.z * kv.z + qv.w * kv.w;
            }
        }
#pragma unroll
        for (int i = 0; i < 32; ++i) ssc[i][jj] = acc[i] * 0.125f;
    }
    __syncthreads();
    const int wv = tid >> 6, ln = tid & 63;
    float rs[8];
#pragma unroll
    for (int r = 0; r < 8; ++r) {
        const int i  = wv * 8 + r;
        const int qi = i0 + i;
        const int lo = max(0, qi - HALFW) - jmin;
        const int hi = min(SEQ - 1, qi + HALFW) - jmin;
        float m = -1e30f;
#pragma unroll
        for (int c = 0; c < 4; ++c) {
            const int j = ln + 64 * c;
            if (j >= lo && j <= hi) m = fmaxf(m, ssc[i][j]);
        }
#pragma unroll
        for (int off = 32; off > 0; off >>= 1) m = fmaxf(m, __shfl_xor(m, off));
        float sum = 0.f;
#pragma unroll
        for (int c = 0; c < 4; ++c) {
            const int j = ln + 64 * c;
            if (j < BWt) {
                float p = 0.f;
                if (j >= lo && j <= hi) p = __expf(ssc[i][j] - m);
                ssc[i][j] = p;
                sum += p;
            }
        }
#pragma unroll
        for (int off = 32; off > 0; off >>= 1) sum += __shfl_xor(sum, off);
        rs[r] = sum;
    }
    float oa[8];
#pragma unroll
    for (int r = 0; r < 8; ++r) oa[r] = 0.f;
    int jq = 0;
    for (; jq + 4 <= BWt; jq += 4) {
        const float v0 = Vbh[(size_t)(jmin + jq + 0) * HDIM + ln];
        const float v1 = Vbh[(size_t)(jmin + jq + 1) * HDIM + ln];
        const float v2 = Vbh[(size_t)(jmin + jq + 2) * HDIM + ln];
        const float v3 = Vbh[(size_t)(jmin + jq + 3) * HDIM + ln];
#pragma unroll
        for (int r = 0; r < 8; ++r) {
            const float4 p4 = *(const float4*)&ssc[wv * 8 + r][jq];
            oa[r] += p4.x * v0 + p4.y * v1 + p4.z * v2 + p4.w * v3;
        }
    }
    for (; jq < BWt; ++jq) {
        const float v0 = Vbh[(size_t)(jmin + jq) * HDIM + ln];
#pragma unroll
        for (int r = 0; r < 8; ++r) oa[r] += ssc[wv * 8 + r][jq] * v0;
    }
#pragma unroll
    for (int r = 0; r < 8; ++r) {
        const int i = i0 + wv * 8 + r;
        O[((size_t)b * SEQ + i) * DMODEL + h * HDIM + ln] = oa[r] / rs[r];
    }
}

// ---------------------------------------------------------------------------
extern "C" void kernel_launch(void* const* d_in, const int* in_sizes, int n_in,
                              void* d_out, int out_size, void* d_ws, size_t ws_size,
                              hipStream_t stream) {
    const float* x  = (const float*)d_in[0];
    const float* Wq = (const float*)d_in[1];
    const float* bq = (const float*)d_in[2];
    const float* Wk = (const float*)d_in[3];
    const float* bk = (const float*)d_in[4];
    const float* Wv = (const float*)d_in[5];
    const float* bv = (const float*)d_in[6];
    const float* Wo = (const float*)d_in[7];
    const float* bo = (const float*)d_in[8];

    float* out = (float*)d_out;

    const size_t REQUIRED = (size_t)80 * 1024 * 1024;
    if (ws_size >= REQUIRED) {
        const size_t M4 = 4194304;                       // 4M u16 = 8MB
        const size_t VT_ELEMS = (size_t)32 * HDIM * VTS; // 4,456,448 u16
        u16* Qb    = (u16*)d_ws;                         // bf16
        u16* Kb    = Qb + M4;                            // bf16
        u16* VTb   = Kb + M4;                            // bf16, padded rows
        u16* aoh   = VTb + VT_ELEMS;                     // fp16
        u16* xh    = aoh + M4;                           // fp16
        u16* wbase = xh + M4;                            // fp16: Wq,Wk,Wv,Wo (4x1M)

        hipMemsetAsync(VTb, 0, VT_ELEMS * sizeof(u16), stream);  // zero pad cols
        split5<<<8192, 256, 0, stream>>>(x, Wq, Wk, Wv, Wo, xh, wbase);
        gemm_qkvf<<<512, 256, 0, stream>>>(xh, wbase, bq, bk, bv, Qb, Kb, VTb);
        attn_mfma<<<1024, 256, 0, stream>>>(Qb, Kb, VTb, aoh);
        gemm_out<<<256, 256, 0, stream>>>(aoh, wbase + 3145728, bo, out);
    } else {
        float* ws = (float*)d_ws;
        const size_t NELEM = (size_t)2 * SEQ * DMODEL;
        float* Qb = ws;
        float* Kb = ws + NELEM;
        float* Vb = ws + 2 * NELEM;
        float* AO = ws + 3 * NELEM;
        gemm_xwt<1><<<512, 256, 0, stream>>>(x, Wq, bq, Qb);
        gemm_xwt<1><<<512, 256, 0, stream>>>(x, Wk, bk, Kb);
        gemm_xwt<1><<<512, 256, 0, stream>>>(x, Wv, bv, Vb);
        attn_local_f32<<<2048, 256, 0, stream>>>(Qb, Kb, Vb, AO);
        gemm_xwt<0><<<512, 256, 0, stream>>>(AO, Wo, bo, out);
    }
}

// Round 18
// 104.810 us; speedup vs baseline: 1.0119x; 1.0119x over previous
//
#include <hip/hip_runtime.h>

// FixedSparseMultiHead: B=2, S=2048, D=1024, H=16, Hd=64, local band ±102.
// Round 18: r16 config (m-major qkvf partition, lower FETCH) + T5 s_setprio
//   around all MFMA clusters (guide: +21-39% on counted-vmcnt phase-split
//   schedules with wave role diversity; +4-7% attn). Zero sync change ->
//   absmax bit-identical.
// Pipeline: split5 -> gemm_qkvf -> attn_mfma (swizzled shared-K) -> gemm_out.
// Fallback fp32 path if ws_size < 80MB.

#define SEQ    2048
#define DMODEL 1024
#define NHEAD  16
#define HDIM   64
#define HALFW  102
#define BWMAX  240
#define VTS    2176    // padded V^T row stride (zeros beyond SEQ)

typedef unsigned short u16;
typedef __attribute__((ext_vector_type(8))) short bf16x8;
typedef __attribute__((ext_vector_type(8))) _Float16 f16x8;
typedef __attribute__((ext_vector_type(4))) float f32x4;

#define VMW12() asm volatile("s_waitcnt vmcnt(12)" ::: "memory")
#define VMW10() asm volatile("s_waitcnt vmcnt(10)" ::: "memory")
#define VMW8()  asm volatile("s_waitcnt vmcnt(8)"  ::: "memory")
#define VMW5()  asm volatile("s_waitcnt vmcnt(5)"  ::: "memory")
#define VMW4()  asm volatile("s_waitcnt vmcnt(4)"  ::: "memory")
#define VMW0()  asm volatile("s_waitcnt vmcnt(0)"  ::: "memory")
#define BARR()  __builtin_amdgcn_s_barrier()
#define CFENCE() asm volatile("" ::: "memory")
#define PRIO1() __builtin_amdgcn_s_setprio(1)
#define PRIO0() __builtin_amdgcn_s_setprio(0)

__device__ __forceinline__ u16 f2bf(float f) {
    unsigned u = __builtin_bit_cast(unsigned, f);
    unsigned r = (u + 0x7fffu + ((u >> 16) & 1u)) >> 16;   // RNE
    return (u16)r;
}
__device__ __forceinline__ float bf2f(u16 u) {
    return __builtin_bit_cast(float, ((unsigned)u) << 16);
}
__device__ __forceinline__ u16 f2h(float f) {
    return __builtin_bit_cast(u16, (_Float16)f);           // RNE
}

__device__ __forceinline__ void gload16(const void* g, void* l) {
    __builtin_amdgcn_global_load_lds(
        (const __attribute__((address_space(1))) void*)g,
        (__attribute__((address_space(3))) void*)l, 16, 0, 0);
}

// ---------------------------------------------------------------------------
// split: fp32 -> fp16. 1-D exact grid 8192: bx<4096 -> x; else weights.
// ---------------------------------------------------------------------------
__global__ __launch_bounds__(256) void split5(
    const float* __restrict__ x,  const float* __restrict__ wq,
    const float* __restrict__ wk, const float* __restrict__ wv,
    const float* __restrict__ wo,
    u16* __restrict__ xh, u16* __restrict__ wbase)
{
    const int bx = blockIdx.x;
    const float* src; u16* dst; int blk;
    if (bx < 4096) {
        src = x; dst = xh; blk = bx;
    } else {
        const int w = (bx - 4096) >> 10;         // 0..3
        blk = (bx - 4096) & 1023;
        switch (w) {
          case 0:  src = wq; dst = wbase;           break;
          case 1:  src = wk; dst = wbase + 1048576; break;
          case 2:  src = wv; dst = wbase + 2097152; break;
          default: src = wo; dst = wbase + 3145728; break;
        }
    }
    const int i = (blk * 256 + threadIdx.x) * 4;
    const float4 v = *(const float4*)(src + i);
    ushort4 h;
    h.x = f2h(v.x); h.y = f2h(v.y); h.z = f2h(v.z); h.w = f2h(v.w);
    *(ushort4*)(dst + i) = h;
}

// ---------------------------------------------------------------------------
// FUSED Q/K/V^T projection (r13/r16-verified structure). Grid 512, 256 thr =
// 4 waves (2m x 2n over 128x64). x-tile staged once for 3 products. BK=32,
// 32 steps. LDS: sA[4][4096] + sB[4][3][2048] = 80 KB -> 2 blk/CU.
// Dist-2 counted vmcnt, one barrier/step. T5 setprio around MFMA cluster.
// ---------------------------------------------------------------------------
__global__ __launch_bounds__(256) void gemm_qkvf(
    const u16* __restrict__ xh, const u16* __restrict__ wbase,
    const float* __restrict__ bq, const float* __restrict__ bk,
    const float* __restrict__ bvv,
    u16* __restrict__ Qo, u16* __restrict__ Ko, u16* __restrict__ VTo)
{
    __shared__ u16 sA[4][4096];      // 32 KB
    __shared__ u16 sB[4][3][2048];   // 48 KB

    const int tid = threadIdx.x, ln = tid & 63, wv = tid >> 6;
    const int wm = wv >> 1, wn = wv & 1;
    const int srow = ln & 15, scol = (ln >> 4) * 8;

    const int bx = blockIdx.x;                  // 512 = 8 XCD x 4 mt x 16 nt
    const int mt = (bx & 7) * 4 + ((bx >> 3) & 3);
    const int nt = bx >> 5;
    const int m0 = mt * 128, n0 = nt * 64;

    f32x4 acc[3][4][2];
#pragma unroll
    for (int y = 0; y < 3; ++y)
#pragma unroll
        for (int fm = 0; fm < 4; ++fm)
#pragma unroll
            for (int fn = 0; fn < 2; ++fn) acc[y][fm][fn] = (f32x4){0.f, 0.f, 0.f, 0.f};

    auto stage = [&](int s) {
        const int buf = s & 3, k0 = s << 5;
#pragma unroll
        for (int i = 0; i < 2; ++i) {           // A: 8 chunks / 4 waves
            const int c = wv * 2 + i;
            gload16(xh + (size_t)(m0 + c * 16 + srow) * 1024 + k0 + scol,
                    sA[buf] + c * 512);
        }
#pragma unroll
        for (int i = 0; i < 3; ++i) {           // B: 12 chunks (3y x 4g) / 4 waves
            const int c = wv * 3 + i;           // 0..11, bijective
            const int yy = c >> 2, g = c & 3;
            gload16(wbase + (size_t)yy * 1048576
                          + (size_t)(n0 + g * 16 + srow) * 1024 + k0 + scol,
                    sB[buf][yy] + g * 512);
        }
    };

    stage(0); stage(1);

    for (int t = 0; t < 32; ++t) {
        if (t + 2 < 32) stage(t + 2);
        if (t < 30)       VMW10();   // stages t+1,t+2 in flight (5 loads each)
        else if (t == 30) VMW5();
        else              VMW0();
        BARR();
        CFENCE();

        const int buf = t & 3;
        f16x8 a[4];
#pragma unroll
        for (int f = 0; f < 4; ++f)
            a[f] = *(const f16x8*)(sA[buf] + (wm * 4 + f) * 512 + ln * 8);
        PRIO1();
#pragma unroll
        for (int y = 0; y < 3; ++y) {
            f16x8 b[2];
#pragma unroll
            for (int f = 0; f < 2; ++f)
                b[f] = *(const f16x8*)(sB[buf][y] + (wn * 2 + f) * 512 + ln * 8);
#pragma unroll
            for (int fm = 0; fm < 4; ++fm)
#pragma unroll
                for (int fn = 0; fn < 2; ++fn)
                    acc[y][fm][fn] = __builtin_amdgcn_mfma_f32_16x16x32_f16(
                        a[fm], b[fn], acc[y][fm][fn], 0, 0, 0);
        }
        PRIO0();
    }

    const int rl = ln & 15, kh = ln >> 4;

    // ---- Q, K epilogue: bf16 [B,H,S,64] ----
#pragma unroll
    for (int y = 0; y < 2; ++y) {
        const float* bias = y ? bk : bq;
        u16* Y = y ? Ko : Qo;
#pragma unroll
        for (int fn = 0; fn < 2; ++fn) {
            const int n = n0 + wn * 32 + fn * 16 + rl;
            const float bb = bias[n];
            const int h = n >> 6, hd = n & 63;
#pragma unroll
            for (int fm = 0; fm < 4; ++fm)
#pragma unroll
                for (int r = 0; r < 4; ++r) {
                    const int m = m0 + wm * 64 + fm * 16 + kh * 4 + r;
                    const int b = m >> 11, s = m & (SEQ - 1);
                    Y[((size_t)(b * NHEAD + h) * SEQ + s) * HDIM + hd] =
                        f2bf(acc[y][fm][fn][r] + bb);
                }
        }
    }
    // ---- V^T epilogue: bf16 [B,H,64,VTS]; C[m=s][n=d] -> VT[d-row][s] ----
#pragma unroll
    for (int fn = 0; fn < 2; ++fn) {
        const int n = n0 + wn * 32 + fn * 16 + rl;   // d index
        const float bb = bvv[n];
        const int h = n >> 6, hd = n & 63;
#pragma unroll
        for (int fm = 0; fm < 4; ++fm)
#pragma unroll
            for (int r = 0; r < 4; ++r) {
                const int m = m0 + wm * 64 + fm * 16 + kh * 4 + r;   // seq index
                const int b = m >> 11, s = m & (SEQ - 1);
                VTo[((size_t)(b * NHEAD + h) * HDIM + hd) * VTS + s] =
                    f2bf(acc[2][fm][fn][r] + bb);
            }
    }
}

// ---------------------------------------------------------------------------
// Final projection (r13-verified): out = AO@Wo^T + bo, fp32 out.
// 5-buffer counted-vmcnt pipeline, BK=32, 128x128 tile, grid 256. T5 setprio.
// ---------------------------------------------------------------------------
__device__ __forceinline__ void gemm_core_out(
    const u16* __restrict__ A, const u16* __restrict__ B,
    int m0, int n0, u16 (*sA)[4096], u16 (*sB)[4096], f32x4 acc[4][4])
{
    const int tid = threadIdx.x, ln = tid & 63, wave = tid >> 6;
    const int wm = wave >> 1, wn = wave & 1;
    const int srow = ln & 15, scol = (ln >> 4) * 8;

#pragma unroll
    for (int fm = 0; fm < 4; ++fm)
#pragma unroll
        for (int fn = 0; fn < 4; ++fn) acc[fm][fn] = (f32x4){0.f, 0.f, 0.f, 0.f};

    auto stage = [&](int s) {
        if (s >= 32) return;
        const int buf = s % 5;
        const int k0 = s << 5;
#pragma unroll
        for (int c = wave; c < 8; c += 4) {
            gload16(A + (size_t)(m0 + c * 16 + srow) * 1024 + k0 + scol, sA[buf] + c * 512);
            gload16(B + (size_t)(n0 + c * 16 + srow) * 1024 + k0 + scol, sB[buf] + c * 512);
        }
    };

    stage(0); stage(1); stage(2);

    int buf = 0;
    for (int t = 0; t < 32; ++t) {
        stage(t + 3);
        if (t < 29)       VMW12();
        else if (t == 29) VMW8();
        else if (t == 30) VMW4();
        else              VMW0();
        BARR();
        CFENCE();

        f16x8 a[4], b[4];
#pragma unroll
        for (int f = 0; f < 4; ++f) {
            a[f] = *(const f16x8*)(sA[buf] + (wm * 4 + f) * 512 + ln * 8);
            b[f] = *(const f16x8*)(sB[buf] + (wn * 4 + f) * 512 + ln * 8);
        }
        PRIO1();
#pragma unroll
        for (int fm = 0; fm < 4; ++fm)
#pragma unroll
            for (int fn = 0; fn < 4; ++fn)
                acc[fm][fn] = __builtin_amdgcn_mfma_f32_16x16x32_f16(
                    a[fm], b[fn], acc[fm][fn], 0, 0, 0);
        PRIO0();
        buf = (buf == 4) ? 0 : buf + 1;
    }
}

__global__ __launch_bounds__(256) void gemm_out(
    const u16* __restrict__ A, const u16* __restrict__ B,
    const float* __restrict__ bias, float* __restrict__ Y)
{
    __shared__ u16 sA[5][4096], sB[5][4096];   // 80 KB
    const int bx = blockIdx.x;
    const int mt = (bx & 7) * 4 + (bx >> 6);
    const int nt = (bx >> 3) & 7;
    const int m0 = mt * 128, n0 = nt * 128;

    f32x4 acc[4][4];
    gemm_core_out(A, B, m0, n0, sA, sB, acc);

    const int tid = threadIdx.x, ln = tid & 63, wave = tid >> 6;
    const int wm = wave >> 1, wn = wave & 1;
    const int rl = ln & 15, kh = ln >> 4;
#pragma unroll
    for (int fn = 0; fn < 4; ++fn) {
        const int n = n0 + wn * 64 + fn * 16 + rl;
        const float bb = bias[n];
#pragma unroll
        for (int fm = 0; fm < 4; ++fm)
#pragma unroll
            for (int r = 0; r < 4; ++r) {
                const int m = m0 + wm * 64 + fm * 16 + kh * 4 + r;
                Y[(size_t)m * DMODEL + n] = acc[fm][fn][r] + bb;
            }
    }
}

// ---------------------------------------------------------------------------
// MFMA banded attention v2 (r16-verified): block-shared swizzled K in LDS,
// P reuses the K buffer after a __syncthreads. 34 KB LDS -> 4 blocks/CU.
// T5 setprio around QK^T and PV MFMA clusters.
// ---------------------------------------------------------------------------
__global__ __launch_bounds__(256) void attn_mfma(
    const u16* __restrict__ Q, const u16* __restrict__ K,
    const u16* __restrict__ VT, u16* __restrict__ aoh)
{
    __shared__ u16 KP[17408];   // 34 KB: K (272 rows x 64 elem), then P

    const int tid = threadIdx.x, ln = tid & 63, wv = tid >> 6;
    const int bx0 = blockIdx.x;
    const int asg = (bx0 & 7) * 128 + (bx0 >> 3);   // 1024 = 8 XCD * 128
    const int bh  = asg >> 5;
    const int qt  = asg & 31;
    const int b   = bh >> 4, h = bh & 15;
    const int q0  = qt * 64 + wv * 16;
    const int jmin = (q0 >= 104) ? (q0 - 104) : 0;         // wave window base
    const int j0   = (qt * 64 >= 104) ? (qt * 64 - 104) : 0; // block window base
    const int woff = jmin - j0;

    const u16* Qbh  = Q  + (size_t)bh * SEQ * HDIM;
    const u16* Kbh  = K  + (size_t)bh * SEQ * HDIM;
    const u16* VTbh = VT + (size_t)bh * HDIM * VTS;

    const int lr = ln & 15, lk = ln >> 4;

    // ---- phase 0: stage K window, swizzled ----
    {
        const int sr = ln >> 3;                 // row within 8-row chunk
        const int scol = ((ln & 7) ^ sr) * 8;   // pre-swizzled source column
        for (int c = wv; c < 34; c += 4) {
            const int j = j0 + c * 8 + sr;
            const int jc = (j < SEQ) ? j : (SEQ - 1);
            gload16(Kbh + (size_t)jc * HDIM + scol, KP + c * 512);
        }
    }

    const bf16x8 qf0 = *(const bf16x8*)(Qbh + (size_t)(q0 + lr) * HDIM + lk * 8);
    const bf16x8 qf1 = *(const bf16x8*)(Qbh + (size_t)(q0 + lr) * HDIM + 32 + lk * 8);

    __syncthreads();   // K staged (drains vmcnt) before any wave reads it

    // ---- phase 1: QK^T from LDS ----
    f32x4 sc[14];
    PRIO1();
#pragma unroll
    for (int t = 0; t < 14; ++t) {
        const int row = woff + t * 16 + lr;     // <= 271
        const int s0 = lk ^ (row & 7);
        const int s1 = (4 + lk) ^ (row & 7);
        const bf16x8 k0 = *(const bf16x8*)(KP + row * 64 + s0 * 8);
        const bf16x8 k1 = *(const bf16x8*)(KP + row * 64 + s1 * 8);
        f32x4 a = (f32x4){0.f, 0.f, 0.f, 0.f};
        a = __builtin_amdgcn_mfma_f32_16x16x32_bf16(qf0, k0, a, 0, 0, 0);
        a = __builtin_amdgcn_mfma_f32_16x16x32_bf16(qf1, k1, a, 0, 0, 0);
        sc[t] = a;
    }
    PRIO0();

    __syncthreads();   // all waves done reading K; P may overwrite buffer

    // ---- phase 1.5: masked softmax; P -> KP as [4][16][232] ----
    u16* P = KP + wv * 3712;
    float lrow[4];
#pragma unroll
    for (int r = 0; r < 4; ++r) {
        const int i = q0 + lk * 4 + r;
        float mx = -3.0e38f;
#pragma unroll
        for (int t = 0; t < 14; ++t) {
            const int j = jmin + t * 16 + lr;
            float v = sc[t][r] * 0.125f;
            const bool ok = (j >= i - HALFW) && (j <= i + HALFW) && (j < SEQ);
            v = ok ? v : -3.0e38f;
            sc[t][r] = v;
            mx = fmaxf(mx, v);
        }
#pragma unroll
        for (int off = 8; off > 0; off >>= 1) mx = fmaxf(mx, __shfl_xor(mx, off));
        float sum = 0.f;
#pragma unroll
        for (int t = 0; t < 14; ++t) {
            const float p = __expf(sc[t][r] - mx);   // masked -> exactly 0
            sum += p;
            P[(lk * 4 + r) * 232 + t * 16 + lr] = f2bf(p);
        }
#pragma unroll
        for (int off = 8; off > 0; off >>= 1) sum += __shfl_xor(sum, off);
        lrow[r] = sum;
    }
    // same-wave LDS write->read below; compiler inserts lgkmcnt waits

    // ---- phase 2: PV, 7 k-chunks x 4 d-tiles, aligned V^T loads ----
    f32x4 ao[4];
#pragma unroll
    for (int nt = 0; nt < 4; ++nt) ao[nt] = (f32x4){0.f, 0.f, 0.f, 0.f};
    PRIO1();
#pragma unroll
    for (int kc = 0; kc < 7; ++kc) {
        const bf16x8 pf = *(const bf16x8*)(P + lr * 232 + kc * 32 + lk * 8);
        const int jb = jmin + kc * 32 + lk * 8;   // 16B aligned, < VTS
#pragma unroll
        for (int nt = 0; nt < 4; ++nt) {
            const bf16x8 vf = *(const bf16x8*)(VTbh + (size_t)(nt * 16 + lr) * VTS + jb);
            ao[nt] = __builtin_amdgcn_mfma_f32_16x16x32_bf16(pf, vf, ao[nt], 0, 0, 0);
        }
    }
    PRIO0();

    // ---- epilogue: AO -> fp16 [4096][1024] ----
#pragma unroll
    for (int nt = 0; nt < 4; ++nt)
#pragma unroll
        for (int r = 0; r < 4; ++r) {
            const int i = q0 + lk * 4 + r;
            const float o = ao[nt][r] / lrow[r];
            aoh[((size_t)b * SEQ + i) * DMODEL + h * HDIM + nt * 16 + lr] = f2h(o);
        }
}

// ---------------------------------------------------------------------------
// Round-1 fp32 path (fallback only).
// ---------------------------------------------------------------------------
template<int QKV>
__global__ __launch_bounds__(256) void gemm_xwt(
    const float* __restrict__ X, const float* __restrict__ W,
    const float* __restrict__ bias, float* __restrict__ Y)
{
    __shared__ float As[16][132];
    __shared__ float Bs[16][68];
    const int tid = threadIdx.x;
    const int bx  = blockIdx.x;
    const int n0  = (bx & 15) * 64;
    const int m0  = (bx >> 4) * 128;
    const int ty  = tid >> 4, tx = tid & 15;
    float acc[8][4];
#pragma unroll
    for (int r = 0; r < 8; ++r)
#pragma unroll
        for (int c = 0; c < 4; ++c) acc[r][c] = 0.f;
    const int lrow = tid >> 2, lkq = (tid & 3) * 4;
    for (int k0 = 0; k0 < DMODEL; k0 += 16) {
        float4 a0 = *(const float4*)(X + (size_t)(m0 + lrow)      * DMODEL + k0 + lkq);
        float4 a1 = *(const float4*)(X + (size_t)(m0 + lrow + 64) * DMODEL + k0 + lkq);
        float4 b0 = *(const float4*)(W + (size_t)(n0 + lrow)      * DMODEL + k0 + lkq);
        __syncthreads();
        As[lkq + 0][lrow] = a0.x; As[lkq + 1][lrow] = a0.y;
        As[lkq + 2][lrow] = a0.z; As[lkq + 3][lrow] = a0.w;
        As[lkq + 0][lrow + 64] = a1.x; As[lkq + 1][lrow + 64] = a1.y;
        As[lkq + 2][lrow + 64] = a1.z; As[lkq + 3][lrow + 64] = a1.w;
        Bs[lkq + 0][lrow] = b0.x; Bs[lkq + 1][lrow] = b0.y;
        Bs[lkq + 2][lrow] = b0.z; Bs[lkq + 3][lrow] = b0.w;
        __syncthreads();
#pragma unroll
        for (int k = 0; k < 16; ++k) {
            float4 av0 = *(const float4*)&As[k][ty * 8];
            float4 av1 = *(const float4*)&As[k][ty * 8 + 4];
            float4 bv  = *(const float4*)&Bs[k][tx * 4];
            float a[8] = {av0.x, av0.y, av0.z, av0.w, av1.x, av1.y, av1.z, av1.w};
            float bb[4] = {bv.x, bv.y, bv.z, bv.w};
#pragma unroll
            for (int r = 0; r < 8; ++r)
#pragma unroll
                for (int c = 0; c < 4; ++c) acc[r][c] += a[r] * bb[c];
        }
    }
    const float4 bb = *(const float4*)(bias + n0 + tx * 4);
    if (QKV) {
        const int b = m0 >> 11, h = n0 >> 6;
#pragma unroll
        for (int r = 0; r < 8; ++r) {
            const int m = m0 + ty * 8 + r, ss = m & (SEQ - 1);
            float4 o = {acc[r][0] + bb.x, acc[r][1] + bb.y, acc[r][2] + bb.z, acc[r][3] + bb.w};
            *(float4*)(Y + ((size_t)(b * NHEAD + h) * SEQ + ss) * HDIM + tx * 4) = o;
        }
    } else {
#pragma unroll
        for (int r = 0; r < 8; ++r) {
            const int m = m0 + ty * 8 + r;
            float4 o = {acc[r][0] + bb.x, acc[r][1] + bb.y, acc[r][2] + bb.z, acc[r][3] + bb.w};
            *(float4*)(Y + (size_t)m * DMODEL + n0 + tx * 4) = o;
        }
    }
}

__global__ __launch_bounds__(256) void attn_local_f32(
    const float* __restrict__ Q, const float* __restrict__ K,
    const float* __restrict__ V, float* __restrict__ O)
{
    __shared__ float ssc[32][BWMAX];
    const int tid = threadIdx.x;
    const int bx0 = blockIdx.x;
    const int bx  = (bx0 & 7) * 256 + (bx0 >> 3);
    const int qt  = bx & 63;
    const int h   = (bx >> 6) & 15;
    const int b   = bx >> 10;
    const int i0  = qt * 32;
    const int jmin = max(0, i0 - HALFW);
    const int jmax = min(SEQ - 1, i0 + 31 + HALFW);
    const int BWt  = jmax - jmin + 1;
    const float* Qbh = Q + (size_t)(b * NHEAD + h) * SEQ * HDIM;
    const float* Kbh = K + (size_t)(b * NHEAD + h) * SEQ * HDIM;
    const float* Vbh = V + (size_t)(b * NHEAD + h) * SEQ * HDIM;
    const int jj = tid;
    if (jj < BWt) {
        float acc[32];
#pragma unroll
        for (int i = 0; i < 32; ++i) acc[i] = 0.f;
        const float* kp = Kbh + (size_t)(jmin + jj) * HDIM;
        for (int d0 = 0; d0 < HDIM; d0 += 4) {
            const float4 kv = *(const float4*)(kp + d0);
#pragma unroll
            for (int i = 0; i < 32; ++i) {
                const float4 qv = *(const float4*)(Qbh + (size_t)(i0 + i) * HDIM + d0);
                acc[i] += qv.x * kv.x + qv.y * kv.y + qv.z * kv.z + qv.w * kv.w;
            }
        }
#pragma unroll
        for (int i = 0; i < 32; ++i) ssc[i][jj] = acc[i] * 0.125f;
    }
    __syncthreads();
    const int wv = tid >> 6, ln = tid & 63;
    float rs[8];
#pragma unroll
    for (int r = 0; r < 8; ++r) {
        const int i  = wv * 8 + r;
        const int qi = i0 + i;
        const int lo = max(0, qi - HALFW) - jmin;
        const int hi = min(SEQ - 1, qi + HALFW) - jmin;
        float m = -1e30f;
#pragma unroll
        for (int c = 0; c < 4; ++c) {
            const int j = ln + 64 * c;
            if (j >= lo && j <= hi) m = fmaxf(m, ssc[i][j]);
        }
#pragma unroll
        for (int off = 32; off > 0; off >>= 1) m = fmaxf(m, __shfl_xor(m, off));
        float sum = 0.f;
#pragma unroll
        for (int c = 0; c < 4; ++c) {
            const int j = ln + 64 * c;
            if (j < BWt) {
                float p = 0.f;
                if (j >= lo && j <= hi) p = __expf(ssc[i][j] - m);
                ssc[i][j] = p;
                sum += p;
            }
        }
#pragma unroll
        for (int off = 32; off > 0; off >>= 1) sum += __shfl_xor(sum, off);
        rs[r] = sum;
    }
    float oa[8];
#pragma unroll
    for (int r = 0; r < 8; ++r) oa[r] = 0.f;
    int jq = 0;
    for (; jq + 4 <= BWt; jq += 4) {
        const float v0 = Vbh[(size_t)(jmin + jq + 0) * HDIM + ln];
        const float v1 = Vbh[(size_t)(jmin + jq + 1) * HDIM + ln];
        const float v2 = Vbh[(size_t)(jmin + jq + 2) * HDIM + ln];
        const float v3 = Vbh[(size_t)(jmin + jq + 3) * HDIM + ln];
#pragma unroll
        for (int r = 0; r < 8; ++r) {
            const float4 p4 = *(const float4*)&ssc[wv * 8 + r][jq];
            oa[r] += p4.x * v0 + p4.y * v1 + p4.z * v2 + p4.w * v3;
        }
    }
    for (; jq < BWt; ++jq) {
        const float v0 = Vbh[(size_t)(jmin + jq) * HDIM + ln];
#pragma unroll
        for (int r = 0; r < 8; ++r) oa[r] += ssc[wv * 8 + r][jq] * v0;
    }
#pragma unroll
    for (int r = 0; r < 8; ++r) {
        const int i = i0 + wv * 8 + r;
        O[((size_t)b * SEQ + i) * DMODEL + h * HDIM + ln] = oa[r] / rs[r];
    }
}

// ---------------------------------------------------------------------------
extern "C" void kernel_launch(void* const* d_in, const int* in_sizes, int n_in,
                              void* d_out, int out_size, void* d_ws, size_t ws_size,
                              hipStream_t stream) {
    const float* x  = (const float*)d_in[0];
    const float* Wq = (const float*)d_in[1];
    const float* bq = (const float*)d_in[2];
    const float* Wk = (const float*)d_in[3];
    const float* bk = (const float*)d_in[4];
    const float* Wv = (const float*)d_in[5];
    const float* bv = (const float*)d_in[6];
    const float* Wo = (const float*)d_in[7];
    const float* bo = (const float*)d_in[8];

    float* out = (float*)d_out;

    const size_t REQUIRED = (size_t)80 * 1024 * 1024;
    if (ws_size >= REQUIRED) {
        const size_t M4 = 4194304;                       // 4M u16 = 8MB
        const size_t VT_ELEMS = (size_t)32 * HDIM * VTS; // 4,456,448 u16
        u16* Qb    = (u16*)d_ws;                         // bf16
        u16* Kb    = Qb + M4;                            // bf16
        u16* VTb   = Kb + M4;                            // bf16, padded rows
        u16* aoh   = VTb + VT_ELEMS;                     // fp16
        u16* xh    = aoh + M4;                           // fp16
        u16* wbase = xh + M4;                            // fp16: Wq,Wk,Wv,Wo (4x1M)

        hipMemsetAsync(VTb, 0, VT_ELEMS * sizeof(u16), stream);  // zero pad cols
        split5<<<8192, 256, 0, stream>>>(x, Wq, Wk, Wv, Wo, xh, wbase);
        gemm_qkvf<<<512, 256, 0, stream>>>(xh, wbase, bq, bk, bv, Qb, Kb, VTb);
        attn_mfma<<<1024, 256, 0, stream>>>(Qb, Kb, VTb, aoh);
        gemm_out<<<256, 256, 0, stream>>>(aoh, wbase + 3145728, bo, out);
    } else {
        float* ws = (float*)d_ws;
        const size_t NELEM = (size_t)2 * SEQ * DMODEL;
        float* Qb = ws;
        float* Kb = ws + NELEM;
        float* Vb = ws + 2 * NELEM;
        float* AO = ws + 3 * NELEM;
        gemm_xwt<1><<<512, 256, 0, stream>>>(x, Wq, bq, Qb);
        gemm_xwt<1><<<512, 256, 0, stream>>>(x, Wk, bk, Kb);
        gemm_xwt<1><<<512, 256, 0, stream>>>(x, Wv, bv, Vb);
        attn_local_f32<<<2048, 256, 0, stream>>>(Qb, Kb, Vb, AO);
        gemm_xwt<0><<<512, 256, 0, stream>>>(AO, Wo, bo, out);
    }
}

// Round 19
// 94.786 us; speedup vs baseline: 1.1189x; 1.1058x over previous
//
#include <hip/hip_runtime.h>

// FixedSparseMultiHead: B=2, S=2048, D=1024, H=16, Hd=64, local band ±102.
// Round 19: qkvf re-tiled 256m x 64n x {Wq,Wk,Wv}, 512 thr (8 waves 4m x 2n).
//   Rationale: staged-traffic accounting shows 327MB vs 14MB ideal at ~5.8TB/s
//   aggregate (L3-class ceiling) - only tile reuse cuts it. W re-read 32->16x
//   (-30% traffic), 192 MFMA/barrier (2x r13's proven amortization), grid 256
//   = 1 block/CU (112KB LDS, 8 waves/CU unchanged).
//   Staging: waves 0-3 stage A (4 chunks), waves 4-7 stage B (3 chunks);
//   per-role counted vmcnt (8/6 steady). Dist-2/4-buffer proof as r13.
//   Same k-order -> absmax bit-identical.
// Pipeline: split5 -> gemm_qkvf -> attn_mfma (swizzled shared-K) -> gemm_out.
// Fallback fp32 path if ws_size < 80MB.

#define SEQ    2048
#define DMODEL 1024
#define NHEAD  16
#define HDIM   64
#define HALFW  102
#define BWMAX  240
#define VTS    2176    // padded V^T row stride (zeros beyond SEQ)

typedef unsigned short u16;
typedef __attribute__((ext_vector_type(8))) short bf16x8;
typedef __attribute__((ext_vector_type(8))) _Float16 f16x8;
typedef __attribute__((ext_vector_type(4))) float f32x4;

#define VMW12() asm volatile("s_waitcnt vmcnt(12)" ::: "memory")
#define VMW8()  asm volatile("s_waitcnt vmcnt(8)"  ::: "memory")
#define VMW6()  asm volatile("s_waitcnt vmcnt(6)"  ::: "memory")
#define VMW4()  asm volatile("s_waitcnt vmcnt(4)"  ::: "memory")
#define VMW3()  asm volatile("s_waitcnt vmcnt(3)"  ::: "memory")
#define VMW0()  asm volatile("s_waitcnt vmcnt(0)"  ::: "memory")
#define BARR()  __builtin_amdgcn_s_barrier()
#define CFENCE() asm volatile("" ::: "memory")
#define PRIO1() __builtin_amdgcn_s_setprio(1)
#define PRIO0() __builtin_amdgcn_s_setprio(0)

__device__ __forceinline__ u16 f2bf(float f) {
    unsigned u = __builtin_bit_cast(unsigned, f);
    unsigned r = (u + 0x7fffu + ((u >> 16) & 1u)) >> 16;   // RNE
    return (u16)r;
}
__device__ __forceinline__ float bf2f(u16 u) {
    return __builtin_bit_cast(float, ((unsigned)u) << 16);
}
__device__ __forceinline__ u16 f2h(float f) {
    return __builtin_bit_cast(u16, (_Float16)f);           // RNE
}

__device__ __forceinline__ void gload16(const void* g, void* l) {
    __builtin_amdgcn_global_load_lds(
        (const __attribute__((address_space(1))) void*)g,
        (__attribute__((address_space(3))) void*)l, 16, 0, 0);
}

// ---------------------------------------------------------------------------
// split: fp32 -> fp16. 1-D exact grid 8192: bx<4096 -> x; else weights.
// ---------------------------------------------------------------------------
__global__ __launch_bounds__(256) void split5(
    const float* __restrict__ x,  const float* __restrict__ wq,
    const float* __restrict__ wk, const float* __restrict__ wv,
    const float* __restrict__ wo,
    u16* __restrict__ xh, u16* __restrict__ wbase)
{
    const int bx = blockIdx.x;
    const float* src; u16* dst; int blk;
    if (bx < 4096) {
        src = x; dst = xh; blk = bx;
    } else {
        const int w = (bx - 4096) >> 10;         // 0..3
        blk = (bx - 4096) & 1023;
        switch (w) {
          case 0:  src = wq; dst = wbase;           break;
          case 1:  src = wk; dst = wbase + 1048576; break;
          case 2:  src = wv; dst = wbase + 2097152; break;
          default: src = wo; dst = wbase + 3145728; break;
        }
    }
    const int i = (blk * 256 + threadIdx.x) * 4;
    const float4 v = *(const float4*)(src + i);
    ushort4 h;
    h.x = f2h(v.x); h.y = f2h(v.y); h.z = f2h(v.z); h.w = f2h(v.w);
    *(ushort4*)(dst + i) = h;
}

// ---------------------------------------------------------------------------
// FUSED Q/K/V^T projection. Grid 256 (= 1 block/CU), 512 thr = 8 waves
// (4m x 2n over 256x64). x-tile staged once for 3 products. BK=32, 32 steps.
// LDS: sA[4][8192] (256x32) + sB[4][3][2048] (3x 64x32) = 112 KB.
//   Chunk = [4 kq][16 row][8 e] = 1KB lane-linear (conflict-free, r5-r18).
// Staging: waves 0-3 stage A chunks wv*4..+3; waves 4-7 stage B chunks
//   (wv-4)*3..+2 (c: yy=c>>2, g=c&3). Dist-2 counted vmcnt (per-role 8/6),
//   one barrier/step; overwrite target of stage(t+2) is buf(t-2), whose
//   reads retired before BARR(t-1) in all waves (proof verified r8/r13).
// ---------------------------------------------------------------------------
__global__ __launch_bounds__(512) void gemm_qkvf(
    const u16* __restrict__ xh, const u16* __restrict__ wbase,
    const float* __restrict__ bq, const float* __restrict__ bk,
    const float* __restrict__ bvv,
    u16* __restrict__ Qo, u16* __restrict__ Ko, u16* __restrict__ VTo)
{
    __shared__ u16 sA[4][8192];      // 64 KB
    __shared__ u16 sB[4][3][2048];   // 48 KB

    const int tid = threadIdx.x, ln = tid & 63, wv = tid >> 6;   // 8 waves
    const int wm = wv >> 1, wn = wv & 1;                         // 4m x 2n
    const int srow = ln & 15, scol = (ln >> 4) * 8;

    const int bx = blockIdx.x;                  // 256 = 8 XCD x 2 mt x 16 nt
    const int mt = (bx & 7) * 2 + ((bx >> 3) & 1);
    const int nt = bx >> 4;
    const int m0 = mt * 256, n0 = nt * 64;

    f32x4 acc[3][4][2];
#pragma unroll
    for (int y = 0; y < 3; ++y)
#pragma unroll
        for (int fm = 0; fm < 4; ++fm)
#pragma unroll
            for (int fn = 0; fn < 2; ++fn) acc[y][fm][fn] = (f32x4){0.f, 0.f, 0.f, 0.f};

    auto stage = [&](int s) {
        const int buf = s & 3, k0 = s << 5;
        if (wv < 4) {
            // A: 16 chunks (256 rows), wave wv stages chunks wv*4..wv*4+3
#pragma unroll
            for (int i = 0; i < 4; ++i) {
                const int c = wv * 4 + i;
                gload16(xh + (size_t)(m0 + c * 16 + srow) * 1024 + k0 + scol,
                        sA[buf] + c * 512);
            }
        } else {
            // B: 12 chunks (3y x 4g), wave wv-4 stages chunks (wv-4)*3..+2
#pragma unroll
            for (int i = 0; i < 3; ++i) {
                const int c = (wv - 4) * 3 + i;   // 0..11
                const int yy = c >> 2, g = c & 3;
                gload16(wbase + (size_t)yy * 1048576
                              + (size_t)(n0 + g * 16 + srow) * 1024 + k0 + scol,
                        sB[buf][yy] + g * 512);
            }
        }
    };

    stage(0); stage(1);

    for (int t = 0; t < 32; ++t) {
        if (t + 2 < 32) stage(t + 2);
        if (t < 30) {                 // stages t+1,t+2 in flight
            if (wv < 4) VMW8(); else VMW6();
        } else if (t == 30) {
            if (wv < 4) VMW4(); else VMW3();
        } else {
            VMW0();
        }
        BARR();
        CFENCE();

        const int buf = t & 3;
        f16x8 a[4];
#pragma unroll
        for (int f = 0; f < 4; ++f)
            a[f] = *(const f16x8*)(sA[buf] + (wm * 4 + f) * 512 + ln * 8);
        PRIO1();
#pragma unroll
        for (int y = 0; y < 3; ++y) {
            f16x8 b[2];
#pragma unroll
            for (int f = 0; f < 2; ++f)
                b[f] = *(const f16x8*)(sB[buf][y] + (wn * 2 + f) * 512 + ln * 8);
#pragma unroll
            for (int fm = 0; fm < 4; ++fm)
#pragma unroll
                for (int fn = 0; fn < 2; ++fn)
                    acc[y][fm][fn] = __builtin_amdgcn_mfma_f32_16x16x32_f16(
                        a[fm], b[fn], acc[y][fm][fn], 0, 0, 0);
        }
        PRIO0();
    }

    const int rl = ln & 15, kh = ln >> 4;

    // ---- Q, K epilogue: bf16 [B,H,S,64] ----
#pragma unroll
    for (int y = 0; y < 2; ++y) {
        const float* bias = y ? bk : bq;
        u16* Y = y ? Ko : Qo;
#pragma unroll
        for (int fn = 0; fn < 2; ++fn) {
            const int n = n0 + wn * 32 + fn * 16 + rl;
            const float bb = bias[n];
            const int h = n >> 6, hd = n & 63;
#pragma unroll
            for (int fm = 0; fm < 4; ++fm)
#pragma unroll
                for (int r = 0; r < 4; ++r) {
                    const int m = m0 + wm * 64 + fm * 16 + kh * 4 + r;
                    const int b = m >> 11, s = m & (SEQ - 1);
                    Y[((size_t)(b * NHEAD + h) * SEQ + s) * HDIM + hd] =
                        f2bf(acc[y][fm][fn][r] + bb);
                }
        }
    }
    // ---- V^T epilogue: bf16 [B,H,64,VTS]; C[m=s][n=d] -> VT[d-row][s] ----
#pragma unroll
    for (int fn = 0; fn < 2; ++fn) {
        const int n = n0 + wn * 32 + fn * 16 + rl;   // d index
        const float bb = bvv[n];
        const int h = n >> 6, hd = n & 63;
#pragma unroll
        for (int fm = 0; fm < 4; ++fm)
#pragma unroll
            for (int r = 0; r < 4; ++r) {
                const int m = m0 + wm * 64 + fm * 16 + kh * 4 + r;   // seq index
                const int b = m >> 11, s = m & (SEQ - 1);
                VTo[((size_t)(b * NHEAD + h) * HDIM + hd) * VTS + s] =
                    f2bf(acc[2][fm][fn][r] + bb);
            }
    }
}

// ---------------------------------------------------------------------------
// Final projection (r13-verified): out = AO@Wo^T + bo, fp32 out.
// 5-buffer counted-vmcnt pipeline, BK=32, 128x128 tile, grid 256.
// ---------------------------------------------------------------------------
__device__ __forceinline__ void gemm_core_out(
    const u16* __restrict__ A, const u16* __restrict__ B,
    int m0, int n0, u16 (*sA)[4096], u16 (*sB)[4096], f32x4 acc[4][4])
{
    const int tid = threadIdx.x, ln = tid & 63, wave = tid >> 6;
    const int wm = wave >> 1, wn = wave & 1;
    const int srow = ln & 15, scol = (ln >> 4) * 8;

#pragma unroll
    for (int fm = 0; fm < 4; ++fm)
#pragma unroll
        for (int fn = 0; fn < 4; ++fn) acc[fm][fn] = (f32x4){0.f, 0.f, 0.f, 0.f};

    auto stage = [&](int s) {
        if (s >= 32) return;
        const int buf = s % 5;
        const int k0 = s << 5;
#pragma unroll
        for (int c = wave; c < 8; c += 4) {
            gload16(A + (size_t)(m0 + c * 16 + srow) * 1024 + k0 + scol, sA[buf] + c * 512);
            gload16(B + (size_t)(n0 + c * 16 + srow) * 1024 + k0 + scol, sB[buf] + c * 512);
        }
    };

    stage(0); stage(1); stage(2);

    int buf = 0;
    for (int t = 0; t < 32; ++t) {
        stage(t + 3);
        if (t < 29)       VMW12();
        else if (t == 29) VMW8();
        else if (t == 30) VMW4();
        else              VMW0();
        BARR();
        CFENCE();

        f16x8 a[4], b[4];
#pragma unroll
        for (int f = 0; f < 4; ++f) {
            a[f] = *(const f16x8*)(sA[buf] + (wm * 4 + f) * 512 + ln * 8);
            b[f] = *(const f16x8*)(sB[buf] + (wn * 4 + f) * 512 + ln * 8);
        }
        PRIO1();
#pragma unroll
        for (int fm = 0; fm < 4; ++fm)
#pragma unroll
            for (int fn = 0; fn < 4; ++fn)
                acc[fm][fn] = __builtin_amdgcn_mfma_f32_16x16x32_f16(
                    a[fm], b[fn], acc[fm][fn], 0, 0, 0);
        PRIO0();
        buf = (buf == 4) ? 0 : buf + 1;
    }
}

__global__ __launch_bounds__(256) void gemm_out(
    const u16* __restrict__ A, const u16* __restrict__ B,
    const float* __restrict__ bias, float* __restrict__ Y)
{
    __shared__ u16 sA[5][4096], sB[5][4096];   // 80 KB
    const int bx = blockIdx.x;
    const int mt = (bx & 7) * 4 + (bx >> 6);
    const int nt = (bx >> 3) & 7;
    const int m0 = mt * 128, n0 = nt * 128;

    f32x4 acc[4][4];
    gemm_core_out(A, B, m0, n0, sA, sB, acc);

    const int tid = threadIdx.x, ln = tid & 63, wave = tid >> 6;
    const int wm = wave >> 1, wn = wave & 1;
    const int rl = ln & 15, kh = ln >> 4;
#pragma unroll
    for (int fn = 0; fn < 4; ++fn) {
        const int n = n0 + wn * 64 + fn * 16 + rl;
        const float bb = bias[n];
#pragma unroll
        for (int fm = 0; fm < 4; ++fm)
#pragma unroll
            for (int r = 0; r < 4; ++r) {
                const int m = m0 + wm * 64 + fm * 16 + kh * 4 + r;
                Y[(size_t)m * DMODEL + n] = acc[fm][fn][r] + bb;
            }
    }
}

// ---------------------------------------------------------------------------
// MFMA banded attention v2 (r16-verified): block-shared swizzled K in LDS,
// P reuses the K buffer after a __syncthreads. 34 KB LDS -> 4 blocks/CU.
// ---------------------------------------------------------------------------
__global__ __launch_bounds__(256) void attn_mfma(
    const u16* __restrict__ Q, const u16* __restrict__ K,
    const u16* __restrict__ VT, u16* __restrict__ aoh)
{
    __shared__ u16 KP[17408];   // 34 KB: K (272 rows x 64 elem), then P

    const int tid = threadIdx.x, ln = tid & 63, wv = tid >> 6;
    const int bx0 = blockIdx.x;
    const int asg = (bx0 & 7) * 128 + (bx0 >> 3);   // 1024 = 8 XCD * 128
    const int bh  = asg >> 5;
    const int qt  = asg & 31;
    const int b   = bh >> 4, h = bh & 15;
    const int q0  = qt * 64 + wv * 16;
    const int jmin = (q0 >= 104) ? (q0 - 104) : 0;         // wave window base
    const int j0   = (qt * 64 >= 104) ? (qt * 64 - 104) : 0; // block window base
    const int woff = jmin - j0;

    const u16* Qbh  = Q  + (size_t)bh * SEQ * HDIM;
    const u16* Kbh  = K  + (size_t)bh * SEQ * HDIM;
    const u16* VTbh = VT + (size_t)bh * HDIM * VTS;

    const int lr = ln & 15, lk = ln >> 4;

    // ---- phase 0: stage K window, swizzled ----
    {
        const int sr = ln >> 3;                 // row within 8-row chunk
        const int scol = ((ln & 7) ^ sr) * 8;   // pre-swizzled source column
        for (int c = wv; c < 34; c += 4) {
            const int j = j0 + c * 8 + sr;
            const int jc = (j < SEQ) ? j : (SEQ - 1);
            gload16(Kbh + (size_t)jc * HDIM + scol, KP + c * 512);
        }
    }

    const bf16x8 qf0 = *(const bf16x8*)(Qbh + (size_t)(q0 + lr) * HDIM + lk * 8);
    const bf16x8 qf1 = *(const bf16x8*)(Qbh + (size_t)(q0 + lr) * HDIM + 32 + lk * 8);

    __syncthreads();   // K staged (drains vmcnt) before any wave reads it

    // ---- phase 1: QK^T from LDS ----
    f32x4 sc[14];
    PRIO1();
#pragma unroll
    for (int t = 0; t < 14; ++t) {
        const int row = woff + t * 16 + lr;     // <= 271
        const int s0 = lk ^ (row & 7);
        const int s1 = (4 + lk) ^ (row & 7);
        const bf16x8 k0 = *(const bf16x8*)(KP + row * 64 + s0 * 8);
        const bf16x8 k1 = *(const bf16x8*)(KP + row * 64 + s1 * 8);
        f32x4 a = (f32x4){0.f, 0.f, 0.f, 0.f};
        a = __builtin_amdgcn_mfma_f32_16x16x32_bf16(qf0, k0, a, 0, 0, 0);
        a = __builtin_amdgcn_mfma_f32_16x16x32_bf16(qf1, k1, a, 0, 0, 0);
        sc[t] = a;
    }
    PRIO0();

    __syncthreads();   // all waves done reading K; P may overwrite buffer

    // ---- phase 1.5: masked softmax; P -> KP as [4][16][232] ----
    u16* P = KP + wv * 3712;
    float lrow[4];
#pragma unroll
    for (int r = 0; r < 4; ++r) {
        const int i = q0 + lk * 4 + r;
        float mx = -3.0e38f;
#pragma unroll
        for (int t = 0; t < 14; ++t) {
            const int j = jmin + t * 16 + lr;
            float v = sc[t][r] * 0.125f;
            const bool ok = (j >= i - HALFW) && (j <= i + HALFW) && (j < SEQ);
            v = ok ? v : -3.0e38f;
            sc[t][r] = v;
            mx = fmaxf(mx, v);
        }
#pragma unroll
        for (int off = 8; off > 0; off >>= 1) mx = fmaxf(mx, __shfl_xor(mx, off));
        float sum = 0.f;
#pragma unroll
        for (int t = 0; t < 14; ++t) {
            const float p = __expf(sc[t][r] - mx);   // masked -> exactly 0
            sum += p;
            P[(lk * 4 + r) * 232 + t * 16 + lr] = f2bf(p);
        }
#pragma unroll
        for (int off = 8; off > 0; off >>= 1) sum += __shfl_xor(sum, off);
        lrow[r] = sum;
    }
    // same-wave LDS write->read below; compiler inserts lgkmcnt waits

    // ---- phase 2: PV, 7 k-chunks x 4 d-tiles, aligned V^T loads ----
    f32x4 ao[4];
#pragma unroll
    for (int nt = 0; nt < 4; ++nt) ao[nt] = (f32x4){0.f, 0.f, 0.f, 0.f};
    PRIO1();
#pragma unroll
    for (int kc = 0; kc < 7; ++kc) {
        const bf16x8 pf = *(const bf16x8*)(P + lr * 232 + kc * 32 + lk * 8);
        const int jb = jmin + kc * 32 + lk * 8;   // 16B aligned, < VTS
#pragma unroll
        for (int nt = 0; nt < 4; ++nt) {
            const bf16x8 vf = *(const bf16x8*)(VTbh + (size_t)(nt * 16 + lr) * VTS + jb);
            ao[nt] = __builtin_amdgcn_mfma_f32_16x16x32_bf16(pf, vf, ao[nt], 0, 0, 0);
        }
    }
    PRIO0();

    // ---- epilogue: AO -> fp16 [4096][1024] ----
#pragma unroll
    for (int nt = 0; nt < 4; ++nt)
#pragma unroll
        for (int r = 0; r < 4; ++r) {
            const int i = q0 + lk * 4 + r;
            const float o = ao[nt][r] / lrow[r];
            aoh[((size_t)b * SEQ + i) * DMODEL + h * HDIM + nt * 16 + lr] = f2h(o);
        }
}

// ---------------------------------------------------------------------------
// Round-1 fp32 path (fallback only).
// ---------------------------------------------------------------------------
template<int QKV>
__global__ __launch_bounds__(256) void gemm_xwt(
    const float* __restrict__ X, const float* __restrict__ W,
    const float* __restrict__ bias, float* __restrict__ Y)
{
    __shared__ float As[16][132];
    __shared__ float Bs[16][68];
    const int tid = threadIdx.x;
    const int bx  = blockIdx.x;
    const int n0  = (bx & 15) * 64;
    const int m0  = (bx >> 4) * 128;
    const int ty  = tid >> 4, tx = tid & 15;
    float acc[8][4];
#pragma unroll
    for (int r = 0; r < 8; ++r)
#pragma unroll
        for (int c = 0; c < 4; ++c) acc[r][c] = 0.f;
    const int lrow = tid >> 2, lkq = (tid & 3) * 4;
    for (int k0 = 0; k0 < DMODEL; k0 += 16) {
        float4 a0 = *(const float4*)(X + (size_t)(m0 + lrow)      * DMODEL + k0 + lkq);
        float4 a1 = *(const float4*)(X + (size_t)(m0 + lrow + 64) * DMODEL + k0 + lkq);
        float4 b0 = *(const float4*)(W + (size_t)(n0 + lrow)      * DMODEL + k0 + lkq);
        __syncthreads();
        As[lkq + 0][lrow] = a0.x; As[lkq + 1][lrow] = a0.y;
        As[lkq + 2][lrow] = a0.z; As[lkq + 3][lrow] = a0.w;
        As[lkq + 0][lrow + 64] = a1.x; As[lkq + 1][lrow + 64] = a1.y;
        As[lkq + 2][lrow + 64] = a1.z; As[lkq + 3][lrow + 64] = a1.w;
        Bs[lkq + 0][lrow] = b0.x; Bs[lkq + 1][lrow] = b0.y;
        Bs[lkq + 2][lrow] = b0.z; Bs[lkq + 3][lrow] = b0.w;
        __syncthreads();
#pragma unroll
        for (int k = 0; k < 16; ++k) {
            float4 av0 = *(const float4*)&As[k][ty * 8];
            float4 av1 = *(const float4*)&As[k][ty * 8 + 4];
            float4 bv  = *(const float4*)&Bs[k][tx * 4];
            float a[8] = {av0.x, av0.y, av0.z, av0.w, av1.x, av1.y, av1.z, av1.w};
            float bb[4] = {bv.x, bv.y, bv.z, bv.w};
#pragma unroll
            for (int r = 0; r < 8; ++r)
#pragma unroll
                for (int c = 0; c < 4; ++c) acc[r][c] += a[r] * bb[c];
        }
    }
    const float4 bb = *(const float4*)(bias + n0 + tx * 4);
    if (QKV) {
        const int b = m0 >> 11, h = n0 >> 6;
#pragma unroll
        for (int r = 0; r < 8; ++r) {
            const int m = m0 + ty * 8 + r, ss = m & (SEQ - 1);
            float4 o = {acc[r][0] + bb.x, acc[r][1] + bb.y, acc[r][2] + bb.z, acc[r][3] + bb.w};
            *(float4*)(Y + ((size_t)(b * NHEAD + h) * SEQ + ss) * HDIM + tx * 4) = o;
        }
    } else {
#pragma unroll
        for (int r = 0; r < 8; ++r) {
            const int m = m0 + ty * 8 + r;
            float4 o = {acc[r][0] + bb.x, acc[r][1] + bb.y, acc[r][2] + bb.z, acc[r][3] + bb.w};
            *(float4*)(Y + (size_t)m * DMODEL + n0 + tx * 4) = o;
        }
    }
}

__global__ __launch_bounds__(256) void attn_local_f32(
    const float* __restrict__ Q, const float* __restrict__ K,
    const float* __restrict__ V, float* __restrict__ O)
{
    __shared__ float ssc[32][BWMAX];
    const int tid = threadIdx.x;
    const int bx0 = blockIdx.x;
    const int bx  = (bx0 & 7) * 256 + (bx0 >> 3);
    const int qt  = bx & 63;
    const int h   = (bx >> 6) & 15;
    const int b   = bx >> 10;
    const int i0  = qt * 32;
    const int jmin = max(0, i0 - HALFW);
    const int jmax = min(SEQ - 1, i0 + 31 + HALFW);
    const int BWt  = jmax - jmin + 1;
    const float* Qbh = Q + (size_t)(b * NHEAD + h) * SEQ * HDIM;
    const float* Kbh = K + (size_t)(b * NHEAD + h) * SEQ * HDIM;
    const float* Vbh = V + (size_t)(b * NHEAD + h) * SEQ * HDIM;
    const int jj = tid;
    if (jj < BWt) {
        float acc[32];
#pragma unroll
        for (int i = 0; i < 32; ++i) acc[i] = 0.f;
        const float* kp = Kbh + (size_t)(jmin + jj) * HDIM;
        for (int d0 = 0; d0 < HDIM; d0 += 4) {
            const float4 kv = *(const float4*)(kp + d0);
#pragma unroll
            for (int i = 0; i < 32; ++i) {
                const float4 qv = *(const float4*)(Qbh + (size_t)(i0 + i) * HDIM + d0);
                acc[i] += qv.x * kv.x + qv.y * kv.y + qv.z * kv.z + qv.w * kv.w;
            }
        }
#pragma unroll
        for (int i = 0; i < 32; ++i) ssc[i][jj] = acc[i] * 0.125f;
    }
    __syncthreads();
    const int wv = tid >> 6, ln = tid & 63;
    float rs[8];
#pragma unroll
    for (int r = 0; r < 8; ++r) {
        const int i  = wv * 8 + r;
        const int qi = i0 + i;
        const int lo = max(0, qi - HALFW) - jmin;
        const int hi = min(SEQ - 1, qi + HALFW) - jmin;
        float m = -1e30f;
#pragma unroll
        for (int c = 0; c < 4; ++c) {
            const int j = ln + 64 * c;
            if (j >= lo && j <= hi) m = fmaxf(m, ssc[i][j]);
        }
#pragma unroll
        for (int off = 32; off > 0; off >>= 1) m = fmaxf(m, __shfl_xor(m, off));
        float sum = 0.f;
#pragma unroll
        for (int c = 0; c < 4; ++c) {
            const int j = ln + 64 * c;
            if (j < BWt) {
                float p = 0.f;
                if (j >= lo && j <= hi) p = __expf(ssc[i][j] - m);
                ssc[i][j] = p;
                sum += p;
            }
        }
#pragma unroll
        for (int off = 32; off > 0; off >>= 1) sum += __shfl_xor(sum, off);
        rs[r] = sum;
    }
    float oa[8];
#pragma unroll
    for (int r = 0; r < 8; ++r) oa[r] = 0.f;
    int jq = 0;
    for (; jq + 4 <= BWt; jq += 4) {
        const float v0 = Vbh[(size_t)(jmin + jq + 0) * HDIM + ln];
        const float v1 = Vbh[(size_t)(jmin + jq + 1) * HDIM + ln];
        const float v2 = Vbh[(size_t)(jmin + jq + 2) * HDIM + ln];
        const float v3 = Vbh[(size_t)(jmin + jq + 3) * HDIM + ln];
#pragma unroll
        for (int r = 0; r < 8; ++r) {
            const float4 p4 = *(const float4*)&ssc[wv * 8 + r][jq];
            oa[r] += p4.x * v0 + p4.y * v1 + p4.z * v2 + p4.w * v3;
        }
    }
    for (; jq < BWt; ++jq) {
        const float v0 = Vbh[(size_t)(jmin + jq) * HDIM + ln];
#pragma unroll
        for (int r = 0; r < 8; ++r) oa[r] += ssc[wv * 8 + r][jq] * v0;
    }
#pragma unroll
    for (int r = 0; r < 8; ++r) {
        const int i = i0 + wv * 8 + r;
        O[((size_t)b * SEQ + i) * DMODEL + h * HDIM + ln] = oa[r] / rs[r];
    }
}

// ---------------------------------------------------------------------------
extern "C" void kernel_launch(void* const* d_in, const int* in_sizes, int n_in,
                              void* d_out, int out_size, void* d_ws, size_t ws_size,
                              hipStream_t stream) {
    const float* x  = (const float*)d_in[0];
    const float* Wq = (const float*)d_in[1];
    const float* bq = (const float*)d_in[2];
    const float* Wk = (const float*)d_in[3];
    const float* bk = (const float*)d_in[4];
    const float* Wv = (const float*)d_in[5];
    const float* bv = (const float*)d_in[6];
    const float* Wo = (const float*)d_in[7];
    const float* bo = (const float*)d_in[8];

    float* out = (float*)d_out;

    const size_t REQUIRED = (size_t)80 * 1024 * 1024;
    if (ws_size >= REQUIRED) {
        const size_t M4 = 4194304;                       // 4M u16 = 8MB
        const size_t VT_ELEMS = (size_t)32 * HDIM * VTS; // 4,456,448 u16
        u16* Qb    = (u16*)d_ws;                         // bf16
        u16* Kb    = Qb + M4;                            // bf16
        u16* VTb   = Kb + M4;                            // bf16, padded rows
        u16* aoh   = VTb + VT_ELEMS;                     // fp16
        u16* xh    = aoh + M4;                           // fp16
        u16* wbase = xh + M4;                            // fp16: Wq,Wk,Wv,Wo (4x1M)

        hipMemsetAsync(VTb, 0, VT_ELEMS * sizeof(u16), stream);  // zero pad cols
        split5<<<8192, 256, 0, stream>>>(x, Wq, Wk, Wv, Wo, xh, wbase);
        gemm_qkvf<<<256, 512, 0, stream>>>(xh, wbase, bq, bk, bv, Qb, Kb, VTb);
        attn_mfma<<<1024, 256, 0, stream>>>(Qb, Kb, VTb, aoh);
        gemm_out<<<256, 256, 0, stream>>>(aoh, wbase + 3145728, bo, out);
    } else {
        float* ws = (float*)d_ws;
        const size_t NELEM = (size_t)2 * SEQ * DMODEL;
        float* Qb = ws;
        float* Kb = ws + NELEM;
        float* Vb = ws + 2 * NELEM;
        float* AO = ws + 3 * NELEM;
        gemm_xwt<1><<<512, 256, 0, stream>>>(x, Wq, bq, Qb);
        gemm_xwt<1><<<512, 256, 0, stream>>>(x, Wk, bk, Kb);
        gemm_xwt<1><<<512, 256, 0, stream>>>(x, Wv, bv, Vb);
        attn_local_f32<<<2048, 256, 0, stream>>>(Qb, Kb, Vb, AO);
        gemm_xwt<0><<<512, 256, 0, stream>>>(AO, Wo, bo, out);
    }
}